// Round 3
// baseline (292.906 us; speedup 1.0000x reference)
//
#include <hip/hip_runtime.h>
#include <cstdint>

#define N_ANCH 8400
#define CBLK 132              // ceil(8400/64)
#define SCORE_THR 0.5f

typedef unsigned long long u64;
typedef unsigned int u32;
typedef unsigned short u16;

// Sort key: ascending sort == (valid score descending, then index ascending,
// invalid last by index ascending) — exactly matches
// argsort(-where(valid, s, -inf)) with stable ties.
__device__ __forceinline__ u64 sort_key(float s, int idx) {
  u32 k32 = (s >= SCORE_THR) ? ~__float_as_uint(s) : 0xFFFFFFFFu;
  return ((u64)k32 << 32) | (u32)idx;
}

__device__ __forceinline__ u64 shfl_u64(u64 v, int src) {
  u32 lo = __shfl((u32)v, src, 64);
  u32 hi = __shfl((u32)(v >> 32), src, 64);
  return ((u64)hi << 32) | lo;
}
__device__ __forceinline__ u64 shfl_xor_u64(u64 v, int m) {
  u32 lo = __shfl_xor((u32)v, m, 64);
  u32 hi = __shfl_xor((u32)(v >> 32), m, 64);
  return ((u64)hi << 32) | lo;
}

// One 64-lane wave per anchor: rank = #{keys smaller}, then scatter
// decoded box + score into sorted position.
__global__ void __launch_bounds__(256) rank_kernel(const float* __restrict__ raw,
                                                   float4* __restrict__ sbox,
                                                   float* __restrict__ sscore) {
  #pragma clang fp contract(off)
  int tid = blockIdx.x * 256 + threadIdx.x;
  int row = tid >> 6, lane = tid & 63;
  if (row >= N_ANCH) return;
  float si = raw[4 * N_ANCH + row];
  u64 ki = sort_key(si, row);
  int cnt = 0;
  for (int j = lane; j < N_ANCH; j += 64) {
    float sj = raw[4 * N_ANCH + j];
    cnt += (sort_key(sj, j) < ki) ? 1 : 0;
  }
  #pragma unroll
  for (int d = 1; d < 64; d <<= 1) cnt += __shfl_xor(cnt, d, 64);
  if (lane == 0) {
    float cx = raw[row], cy = raw[N_ANCH + row];
    float w = raw[2 * N_ANCH + row], h = raw[3 * N_ANCH + row];
    float hw = w * 0.5f, hh = h * 0.5f;
    sbox[cnt] = make_float4(cx - hw, cy - hh, cx + hw, cy + hh);
    sscore[cnt] = si;
  }
}

// Suppression bitmask over sorted boxes. 256 threads = 256 rows x 64 cols
// per block; grid (CBLK, 33). mask[i*CBLK+cb] bit jj set iff j=cb*64+jj has
// j>i, j<N, iou(i,j) > 0.5. Skips: tiles entirely below the diagonal, tiles
// whose rows are all invalid, tiles whose cols are all invalid (scores are
// sorted descending, so validity is a prefix).
__global__ void __launch_bounds__(256) mask_kernel(const float4* __restrict__ sbox,
                                                   const float* __restrict__ sscore,
                                                   u64* __restrict__ mask) {
  #pragma clang fp contract(off)
  int cb = blockIdx.x;
  int i0 = blockIdx.y * 256;
  if (cb * 64 + 63 < i0) return;                 // j <= i for every pair: never read
  if (!(sscore[i0] >= SCORE_THR)) return;        // all rows invalid
  if (!(sscore[cb * 64] >= SCORE_THR)) return;   // all cols invalid -> never read
  int t = threadIdx.x;
  __shared__ float4 cbox[64];
  __shared__ float carea[64];
  int j0 = cb * 64;
  if (t < 64) {
    int j = j0 + t;
    float4 bj = (j < N_ANCH) ? sbox[j] : make_float4(0.f, 0.f, 0.f, 0.f);
    cbox[t] = bj;
    carea[t] = (bj.z - bj.x) * (bj.w - bj.y);
  }
  __syncthreads();
  int i = i0 + t;
  if (i >= N_ANCH || i >= (cb + 1) * 64) return; // rows whose block > cb: never read
  float4 bi = sbox[i];
  float ai = (bi.z - bi.x) * (bi.w - bi.y);
  u64 word = 0;
  for (int jj = 0; jj < 64; ++jj) {
    int jg = j0 + jj;
    if (jg <= i || jg >= N_ANCH) continue;
    float4 bb = cbox[jj];
    float ltx = fmaxf(bi.x, bb.x), lty = fmaxf(bi.y, bb.y);
    float rbx = fminf(bi.z, bb.z), rby = fminf(bi.w, bb.w);
    float wx = fmaxf(rbx - ltx, 0.f), wy = fmaxf(rby - lty, 0.f);
    float inter = wx * wy;
    float uni = (ai + carea[jj]) - inter;      // same op order as reference
    float iou = inter / fmaxf(uni, 1e-9f);     // IEEE div, matches numpy
    if (iou > 0.5f) word |= (1ull << jj);
  }
  mask[(u64)i * CBLK + cb] = word;
}

// Single WAVE (64 threads), wave-synchronous (no barriers in the hot loop).
//  - n_valid found by 2-round sorted-prefix probe (4 global loads total)
//  - removed word per block: manually unrolled predicated gather over the
//    kept-row list -> all loads in flight, ~one L3 latency per block
//  - greedy scan: diagonal mask words in registers, shfl_u64 broadcast chain
__global__ void __launch_bounds__(64) nms_kernel(const float4* __restrict__ sbox,
                                                 const float* __restrict__ sscore,
                                                 const u64* __restrict__ mask,
                                                 float* __restrict__ out) {
  __shared__ u64 keepw[CBLK];
  __shared__ u16 krow[8448];     // kept rows in sorted order
  int lane = threadIdx.x;

  // ---- n_valid via 2-round probe (scores sorted desc => validity is prefix)
  float s0 = sscore[lane * 132];                 // 63*132 = 8316 < 8400
  u64 b0 = __ballot(s0 >= SCORE_THR);
  int cnt1 = (int)__popcll(b0);
  int n_valid = 0;
  if (cnt1 > 0) {
    int a = (cnt1 - 1) * 132 + 1;                // rows < a known valid
    int i1 = a + 3 * lane;                       // 3 probes/lane cover 192 >= 132
    float t1 = (i1 + 0 < N_ANCH) ? sscore[i1 + 0] : -1.f;
    float t2 = (i1 + 1 < N_ANCH) ? sscore[i1 + 1] : -1.f;
    float t3 = (i1 + 2 < N_ANCH) ? sscore[i1 + 2] : -1.f;
    u64 q1 = __ballot(t1 >= SCORE_THR);
    u64 q2 = __ballot(t2 >= SCORE_THR);
    u64 q3 = __ballot(t3 >= SCORE_THR);
    n_valid = a + (int)__popcll(q1) + (int)__popcll(q2) + (int)__popcll(q3);
  }
  int VB = (n_valid + 63) >> 6;                  // number of valid blocks

  for (int b = lane; b < CBLK; b += 64) keepw[b] = 0;
  if (lane == 0) krow[0] = 0;
  __syncthreads();                               // single wave: cheap, safe

  int nk = 0;
  for (int b = 0; b < VB; ++b) {
    int rem = n_valid - b * 64;                  // >= 1 since b < VB
    u64 vmask = (rem >= 64) ? ~0ull : ((1ull << rem) - 1ull);
    // diagonal mask words into registers (overlaps gather latency)
    int r = b * 64 + lane;
    u64 mw = (r < N_ANCH) ? mask[(u64)r * CBLK + b] : 0;
    // gather removed-word contributions from all kept rows, fully unrolled
    u64 acc = 0;
    for (int g = 0; g < nk; g += 512) {
      #pragma unroll
      for (int u = 0; u < 8; ++u) {
        int i = g + u * 64 + lane;
        int ic = (i < nk) ? i : 0;
        u64 v = mask[(u64)krow[ic] * CBLK + b];
        acc |= (i < nk) ? v : 0ull;
      }
    }
    #pragma unroll
    for (int d = 1; d < 64; d <<= 1) acc |= shfl_xor_u64(acc, d);
    u64 act = vmask & ~acc;
    u64 kw = 0;
    u64 a = act;
    while (a) {                                  // iterations == kept in block
      int l = (int)__builtin_ctzll(a);
      kw |= (1ull << l);
      a &= ~(1ull << l);
      a &= ~shfl_u64(mw, l);                     // suppressed by kept row l
    }
    if (lane == 0) keepw[b] = kw;
    if ((kw >> lane) & 1ull) {
      int pfx = (int)__popcll(kw & ((1ull << lane) - 1ull));
      krow[nk + pfx] = (u16)r;
    }
    nk += (int)__popcll(kw);
  }
  __syncthreads();

  // fused masked output
  for (int r2 = lane; r2 < N_ANCH; r2 += 64) {
    u64 kv = keepw[r2 >> 6];
    bool kp = (kv >> (r2 & 63)) & 1ull;
    float4 b4 = sbox[r2];
    float sc = sscore[r2];
    float* o = out + r2 * 5;
    o[0] = kp ? b4.x : 0.f;
    o[1] = kp ? b4.y : 0.f;
    o[2] = kp ? b4.z : 0.f;
    o[3] = kp ? b4.w : 0.f;
    o[4] = kp ? sc : 0.f;
  }
}

extern "C" void kernel_launch(void* const* d_in, const int* in_sizes, int n_in,
                              void* d_out, int out_size, void* d_ws, size_t ws_size,
                              hipStream_t stream) {
  const float* raw = (const float*)d_in[0];
  float* out = (float*)d_out;
  char* ws = (char*)d_ws;
  // ws layout: sbox (8448*16 B) | sscore (8448*4 B) | mask (8400*132*8 B) ≈ 9.04 MB
  float4* sbox = (float4*)ws;
  float* sscore = (float*)(ws + 8448 * 16);
  u64* mask = (u64*)(ws + 8448 * 16 + 8448 * 4);

  rank_kernel<<<2100, 256, 0, stream>>>(raw, sbox, sscore);
  mask_kernel<<<dim3(CBLK, 33), 256, 0, stream>>>(sbox, sscore, mask);
  nms_kernel<<<1, 64, 0, stream>>>(sbox, sscore, mask, out);
}